// Round 1
// baseline (2366.514 us; speedup 1.0000x reference)
//
#include <hip/hip_runtime.h>

// Problem constants (from reference)
#define USER_N   100000
#define ITEM_N   200000
#define LATDIM   128
#define N_TOTAL  (USER_N + ITEM_N)   // 300000
#define N_EDGES_C  600000
#define UU_EDGES_C 300000

// ---------------------------------------------------------------------------
// init: cur = acc = concat(uEmbeds0, iEmbeds0)   (float4-vectorized)
// ---------------------------------------------------------------------------
__global__ void init_concat_kernel(const float4* __restrict__ u,
                                   const float4* __restrict__ it,
                                   float4* __restrict__ cur,
                                   float4* __restrict__ acc,
                                   int n4, int ubound4) {
    int idx = blockIdx.x * blockDim.x + threadIdx.x;
    if (idx >= n4) return;
    float4 v = (idx < ubound4) ? u[idx] : it[idx - ubound4];
    cur[idx] = v;
    acc[idx] = v;
}

// init: a = b = src  (for the user-user branch)
__global__ void init_copy2_kernel(const float4* __restrict__ src,
                                  float4* __restrict__ a,
                                  float4* __restrict__ b,
                                  int n4) {
    int idx = blockIdx.x * blockDim.x + threadIdx.x;
    if (idx >= n4) return;
    float4 v = src[idx];
    a[idx] = v;
    b[idx] = v;
}

// ---------------------------------------------------------------------------
// Scatter SpMM: one 64-lane wave per edge, float2 per lane (128 dims).
// y[row, :] += val * x[col, :]   via atomicAdd (y must be pre-zeroed).
// ---------------------------------------------------------------------------
__global__ void spmm_scatter_kernel(const int* __restrict__ rows,
                                    const int* __restrict__ cols,
                                    const float* __restrict__ vals,
                                    const float* __restrict__ x,
                                    float* __restrict__ y,
                                    int n_edges) {
    long long t = (long long)blockIdx.x * blockDim.x + threadIdx.x;
    int edge = (int)(t >> 6);
    int lane = (int)(t & 63);
    if (edge >= n_edges) return;

    int   r = rows[edge];        // wave-uniform loads (whole wave = one edge)
    int   c = cols[edge];
    float v = vals[edge];

    const float2* xp = (const float2*)(x + (size_t)c * LATDIM);
    float2 xv = xp[lane];                       // coalesced 512B per edge

    float* yp = y + (size_t)r * LATDIM + (size_t)lane * 2;
    atomicAdd(yp,     v * xv.x);
    atomicAdd(yp + 1, v * xv.y);
}

// acc += b   (float4-vectorized)
__global__ void axpy_acc_kernel(float4* __restrict__ acc,
                                const float4* __restrict__ b,
                                int n4) {
    int idx = blockIdx.x * blockDim.x + threadIdx.x;
    if (idx >= n4) return;
    float4 a = acc[idx];
    float4 x = b[idx];
    a.x += x.x; a.y += x.y; a.z += x.z; a.w += x.w;
    acc[idx] = a;
}

// ---------------------------------------------------------------------------
extern "C" void kernel_launch(void* const* d_in, const int* in_sizes, int n_in,
                              void* d_out, int out_size, void* d_ws, size_t ws_size,
                              hipStream_t stream) {
    const float* uE    = (const float*)d_in[0];
    const float* iE    = (const float*)d_in[1];
    const int*   arows = (const int*)  d_in[2];
    const int*   acols = (const int*)  d_in[3];
    const float* avals = (const float*)d_in[4];
    const int*   urows = (const int*)  d_in[5];
    const int*   ucols = (const int*)  d_in[6];
    const float* uvals = (const float*)d_in[7];

    // Output layout: [acc (N_TOTAL x 128)] [uacc (USER_N x 128)]
    float* acc  = (float*)d_out;
    float* uacc = acc + (size_t)N_TOTAL * LATDIM;

    // Workspace: two ping-pong embedding buffers (N_TOTAL x 128 each, 307 MB)
    float* A = (float*)d_ws;
    float* B = A + (size_t)N_TOTAL * LATDIM;

    const int TB = 256;
    const int n4 = N_TOTAL * (LATDIM / 4);   // 9.6M float4
    const int u4 = USER_N  * (LATDIM / 4);   // 3.2M float4

    // ---- main graph: acc = e0 + A e0 + A^2 e0 + A^3 e0 -----------------
    init_concat_kernel<<<(n4 + TB - 1) / TB, TB, 0, stream>>>(
        (const float4*)uE, (const float4*)iE, (float4*)A, (float4*)acc, n4, u4);

    for (int l = 0; l < 3; ++l) {
        hipMemsetAsync(B, 0, (size_t)N_TOTAL * LATDIM * sizeof(float), stream);
        int threads = N_EDGES_C * 64;
        spmm_scatter_kernel<<<(threads + TB - 1) / TB, TB, 0, stream>>>(
            arows, acols, avals, A, B, N_EDGES_C);
        axpy_acc_kernel<<<(n4 + TB - 1) / TB, TB, 0, stream>>>(
            (float4*)acc, (const float4*)B, n4);
        float* tmp = A; A = B; B = tmp;
    }

    // ---- user-user graph: uacc = u0 + U u0 + U^2 u0 --------------------
    init_copy2_kernel<<<(u4 + TB - 1) / TB, TB, 0, stream>>>(
        (const float4*)uE, (float4*)A, (float4*)uacc, u4);

    for (int l = 0; l < 2; ++l) {
        hipMemsetAsync(B, 0, (size_t)USER_N * LATDIM * sizeof(float), stream);
        int threads = UU_EDGES_C * 64;
        spmm_scatter_kernel<<<(threads + TB - 1) / TB, TB, 0, stream>>>(
            urows, ucols, uvals, A, B, UU_EDGES_C);
        axpy_acc_kernel<<<(u4 + TB - 1) / TB, TB, 0, stream>>>(
            (float4*)uacc, (const float4*)B, u4);
        float* tmp = A; A = B; B = tmp;
    }
}

// Round 2
// 756.540 us; speedup vs baseline: 3.1281x; 3.1281x over previous
//
#include <hip/hip_runtime.h>

#define USER_N   100000
#define ITEM_N   200000
#define LATDIM   128
#define N_TOTAL  (USER_N + ITEM_N)   // 300000
#define N_EDGES_C  600000
#define UU_EDGES_C 300000
#define SCAN_B   256

// ---------------------------------------------------------------------------
// init: cur = acc = concat(uEmbeds0, iEmbeds0)
// ---------------------------------------------------------------------------
__global__ void init_concat_kernel(const float4* __restrict__ u,
                                   const float4* __restrict__ it,
                                   float4* __restrict__ cur,
                                   float4* __restrict__ acc,
                                   int n4, int ubound4) {
    int idx = blockIdx.x * blockDim.x + threadIdx.x;
    if (idx >= n4) return;
    float4 v = (idx < ubound4) ? u[idx] : it[idx - ubound4];
    cur[idx] = v;
    acc[idx] = v;
}

__global__ void init_copy2_kernel(const float4* __restrict__ src,
                                  float4* __restrict__ a,
                                  float4* __restrict__ b,
                                  int n4) {
    int idx = blockIdx.x * blockDim.x + threadIdx.x;
    if (idx >= n4) return;
    float4 v = src[idx];
    a[idx] = v;
    b[idx] = v;
}

// ---------------------------------------------------------------------------
// CSR build: histogram -> exclusive scan -> scatter
// ---------------------------------------------------------------------------
__global__ void hist_kernel(const int* __restrict__ rows, int* __restrict__ cnt,
                            int n_edges) {
    int i = blockIdx.x * blockDim.x + threadIdx.x;
    if (i < n_edges) atomicAdd(&cnt[rows[i]], 1);
}

// per-block exclusive scan; block totals to bsum
__global__ void scan_block_kernel(const int* __restrict__ cnt,
                                  int* __restrict__ rptr,
                                  int* __restrict__ bsum, int n) {
    __shared__ int s[SCAN_B];
    int i = blockIdx.x * SCAN_B + threadIdx.x;
    int v = (i < n) ? cnt[i] : 0;
    s[threadIdx.x] = v;
    __syncthreads();
    for (int off = 1; off < SCAN_B; off <<= 1) {
        int t = (threadIdx.x >= off) ? s[threadIdx.x - off] : 0;
        __syncthreads();
        s[threadIdx.x] += t;
        __syncthreads();
    }
    if (i < n) rptr[i] = s[threadIdx.x] - v;          // exclusive
    if (threadIdx.x == SCAN_B - 1) bsum[blockIdx.x] = s[threadIdx.x];
}

// single-block serial-chunked exclusive scan of block sums
__global__ void scan_bsum_kernel(int* __restrict__ bsum, int nb) {
    __shared__ int s[SCAN_B];
    __shared__ int carry;
    if (threadIdx.x == 0) carry = 0;
    __syncthreads();
    for (int base = 0; base < nb; base += SCAN_B) {
        int i = base + threadIdx.x;
        int v = (i < nb) ? bsum[i] : 0;
        s[threadIdx.x] = v;
        __syncthreads();
        for (int off = 1; off < SCAN_B; off <<= 1) {
            int t = (threadIdx.x >= off) ? s[threadIdx.x - off] : 0;
            __syncthreads();
            s[threadIdx.x] += t;
            __syncthreads();
        }
        if (i < nb) bsum[i] = s[threadIdx.x] - v + carry;
        __syncthreads();
        if (threadIdx.x == 0) carry += s[SCAN_B - 1];
        __syncthreads();
    }
}

__global__ void scan_add_kernel(int* __restrict__ rptr, const int* __restrict__ bsum,
                                int* __restrict__ cursor, int n, int n_edges) {
    int i = blockIdx.x * blockDim.x + threadIdx.x;
    if (i < n) {
        int v = rptr[i] + bsum[i / SCAN_B];
        rptr[i]   = v;
        cursor[i] = v;
    }
    if (i == 0) rptr[n] = n_edges;
}

__global__ void scatter_kernel(const int* __restrict__ rows, const int* __restrict__ cols,
                               const float* __restrict__ vals,
                               int* __restrict__ cursor,
                               int* __restrict__ scol, float* __restrict__ sval,
                               int n_edges) {
    int i = blockIdx.x * blockDim.x + threadIdx.x;
    if (i >= n_edges) return;
    int r = rows[i];
    int pos = atomicAdd(&cursor[r], 1);
    scol[pos] = cols[i];
    sval[pos] = vals[i];
}

// ---------------------------------------------------------------------------
// Gather SpMM: 32 lanes per row, float4/lane (128 dims). Atomic-free.
// cur[r] = sum_e val*x[col];  acc[r] += cur[r]   (fused axpy)
// ---------------------------------------------------------------------------
__global__ void spmm_gather_kernel(const int* __restrict__ rptr,
                                   const int* __restrict__ scol,
                                   const float* __restrict__ sval,
                                   const float4* __restrict__ x,
                                   float4* __restrict__ cur,
                                   float4* __restrict__ acc,
                                   int n_rows) {
    int t = blockIdx.x * blockDim.x + threadIdx.x;
    int r   = t >> 5;
    int sub = t & 31;
    if (r >= n_rows) return;

    int e0 = rptr[r];
    int e1 = rptr[r + 1];

    float4 a = make_float4(0.f, 0.f, 0.f, 0.f);
    for (int e = e0; e < e1; ++e) {
        int   c = scol[e];
        float v = sval[e];
        float4 xv = x[(size_t)c * 32 + sub];      // 512B coalesced per 32-lane group
        a.x += v * xv.x; a.y += v * xv.y; a.z += v * xv.z; a.w += v * xv.w;
    }
    size_t o = (size_t)r * 32 + sub;
    cur[o] = a;
    float4 ac = acc[o];
    ac.x += a.x; ac.y += a.y; ac.z += a.z; ac.w += a.w;
    acc[o] = ac;
}

// ---------------------------------------------------------------------------
extern "C" void kernel_launch(void* const* d_in, const int* in_sizes, int n_in,
                              void* d_out, int out_size, void* d_ws, size_t ws_size,
                              hipStream_t stream) {
    const float* uE    = (const float*)d_in[0];
    const float* iE    = (const float*)d_in[1];
    const int*   arows = (const int*)  d_in[2];
    const int*   acols = (const int*)  d_in[3];
    const float* avals = (const float*)d_in[4];
    const int*   urows = (const int*)  d_in[5];
    const int*   ucols = (const int*)  d_in[6];
    const float* uvals = (const float*)d_in[7];

    float* acc  = (float*)d_out;                              // N_TOTAL x 128
    float* uacc = acc + (size_t)N_TOTAL * LATDIM;             // USER_N x 128

    // workspace layout
    float* A    = (float*)d_ws;                               // N_TOTAL*128
    float* B    = A + (size_t)N_TOTAL * LATDIM;               // N_TOTAL*128
    int*   cnt  = (int*)(B + (size_t)N_TOTAL * LATDIM);       // N_TOTAL
    int*   rptr = cnt + N_TOTAL;                              // N_TOTAL+1
    int*   curp = rptr + N_TOTAL + 1;                         // N_TOTAL (cursor)
    int*   bsum = curp + N_TOTAL;                             // 4096
    int*   scol = bsum + 4096;                                // N_EDGES
    float* sval = (float*)(scol + N_EDGES_C);                 // N_EDGES

    const int TB = 256;
    const int n4 = N_TOTAL * (LATDIM / 4);
    const int u4 = USER_N  * (LATDIM / 4);

    // ================= main graph =================
    init_concat_kernel<<<(n4 + TB - 1) / TB, TB, 0, stream>>>(
        (const float4*)uE, (const float4*)iE, (float4*)A, (float4*)acc, n4, u4);

    hipMemsetAsync(cnt, 0, N_TOTAL * sizeof(int), stream);
    hist_kernel<<<(N_EDGES_C + TB - 1) / TB, TB, 0, stream>>>(arows, cnt, N_EDGES_C);
    {
        int nb = (N_TOTAL + SCAN_B - 1) / SCAN_B;
        scan_block_kernel<<<nb, SCAN_B, 0, stream>>>(cnt, rptr, bsum, N_TOTAL);
        scan_bsum_kernel<<<1, SCAN_B, 0, stream>>>(bsum, nb);
        scan_add_kernel<<<(N_TOTAL + TB - 1) / TB, TB, 0, stream>>>(
            rptr, bsum, curp, N_TOTAL, N_EDGES_C);
    }
    scatter_kernel<<<(N_EDGES_C + TB - 1) / TB, TB, 0, stream>>>(
        arows, acols, avals, curp, scol, sval, N_EDGES_C);

    for (int l = 0; l < 3; ++l) {
        int threads = N_TOTAL * 32;
        spmm_gather_kernel<<<(threads + TB - 1) / TB, TB, 0, stream>>>(
            rptr, scol, sval, (const float4*)A, (float4*)B, (float4*)acc, N_TOTAL);
        float* tmp = A; A = B; B = tmp;
    }

    // ================= user-user graph =================
    A = (float*)d_ws;                     // reset ping-pong (buffers free now)
    B = A + (size_t)N_TOTAL * LATDIM;

    init_copy2_kernel<<<(u4 + TB - 1) / TB, TB, 0, stream>>>(
        (const float4*)uE, (float4*)A, (float4*)uacc, u4);

    hipMemsetAsync(cnt, 0, USER_N * sizeof(int), stream);
    hist_kernel<<<(UU_EDGES_C + TB - 1) / TB, TB, 0, stream>>>(urows, cnt, UU_EDGES_C);
    {
        int nb = (USER_N + SCAN_B - 1) / SCAN_B;
        scan_block_kernel<<<nb, SCAN_B, 0, stream>>>(cnt, rptr, bsum, USER_N);
        scan_bsum_kernel<<<1, SCAN_B, 0, stream>>>(bsum, nb);
        scan_add_kernel<<<(USER_N + TB - 1) / TB, TB, 0, stream>>>(
            rptr, bsum, curp, USER_N, UU_EDGES_C);
    }
    scatter_kernel<<<(UU_EDGES_C + TB - 1) / TB, TB, 0, stream>>>(
        urows, ucols, uvals, curp, scol, sval, UU_EDGES_C);

    for (int l = 0; l < 2; ++l) {
        int threads = USER_N * 32;
        spmm_gather_kernel<<<(threads + TB - 1) / TB, TB, 0, stream>>>(
            rptr, scol, sval, (const float4*)A, (float4*)B, (float4*)uacc, USER_N);
        float* tmp = A; A = B; B = tmp;
    }
}

// Round 3
// 588.350 us; speedup vs baseline: 4.0223x; 1.2859x over previous
//
#include <hip/hip_runtime.h>

#define USER_N   100000
#define ITEM_N   200000
#define LATDIM   128
#define NV4      (LATDIM / 4)        // 32 float4 per row
#define N_TOTAL  (USER_N + ITEM_N)   // 300000
#define N_EDGES_C  600000
#define UU_EDGES_C 300000
#define SCAN_B   256

// ---------------------------------------------------------------------------
// CSR build: histogram -> exclusive scan -> scatter
// ---------------------------------------------------------------------------
__global__ void hist_kernel(const int* __restrict__ rows, int* __restrict__ cnt,
                            int n_edges) {
    int i = blockIdx.x * blockDim.x + threadIdx.x;
    if (i < n_edges) atomicAdd(&cnt[rows[i]], 1);
}

__global__ void scan_block_kernel(const int* __restrict__ cnt,
                                  int* __restrict__ rptr,
                                  int* __restrict__ bsum, int n) {
    __shared__ int s[SCAN_B];
    int i = blockIdx.x * SCAN_B + threadIdx.x;
    int v = (i < n) ? cnt[i] : 0;
    s[threadIdx.x] = v;
    __syncthreads();
    for (int off = 1; off < SCAN_B; off <<= 1) {
        int t = (threadIdx.x >= off) ? s[threadIdx.x - off] : 0;
        __syncthreads();
        s[threadIdx.x] += t;
        __syncthreads();
    }
    if (i < n) rptr[i] = s[threadIdx.x] - v;          // exclusive
    if (threadIdx.x == SCAN_B - 1) bsum[blockIdx.x] = s[threadIdx.x];
}

__global__ void scan_bsum_kernel(int* __restrict__ bsum, int nb) {
    __shared__ int s[SCAN_B];
    __shared__ int carry;
    if (threadIdx.x == 0) carry = 0;
    __syncthreads();
    for (int base = 0; base < nb; base += SCAN_B) {
        int i = base + threadIdx.x;
        int v = (i < nb) ? bsum[i] : 0;
        s[threadIdx.x] = v;
        __syncthreads();
        for (int off = 1; off < SCAN_B; off <<= 1) {
            int t = (threadIdx.x >= off) ? s[threadIdx.x - off] : 0;
            __syncthreads();
            s[threadIdx.x] += t;
            __syncthreads();
        }
        if (i < nb) bsum[i] = s[threadIdx.x] - v + carry;
        __syncthreads();
        if (threadIdx.x == 0) carry += s[SCAN_B - 1];
        __syncthreads();
    }
}

__global__ void scan_add_kernel(int* __restrict__ rptr, const int* __restrict__ bsum,
                                int* __restrict__ cursor, int n, int n_edges) {
    int i = blockIdx.x * blockDim.x + threadIdx.x;
    if (i < n) {
        int v = rptr[i] + bsum[i / SCAN_B];
        rptr[i]   = v;
        cursor[i] = v;
    }
    if (i == 0) rptr[n] = n_edges;
}

__global__ void scatter_kernel(const int* __restrict__ rows, const int* __restrict__ cols,
                               const float* __restrict__ vals,
                               int* __restrict__ cursor,
                               int* __restrict__ scol, float* __restrict__ sval,
                               int n_edges) {
    int i = blockIdx.x * blockDim.x + threadIdx.x;
    if (i >= n_edges) return;
    int r = rows[i];
    int pos = atomicAdd(&cursor[r], 1);
    scol[pos] = cols[i];
    sval[pos] = vals[i];
}

// ---------------------------------------------------------------------------
// Gather SpMM, 32 lanes/row, float4/lane, 2-way unrolled (dual accumulators).
// FIRST: gather from concat(x1,x2) split at ubound; acc = e0[r] + cur (no acc read).
// else : gather from x1;                            acc += cur.
// WRITE_CUR=false on each graph's last layer.
// ---------------------------------------------------------------------------
__device__ __forceinline__ const float4* sel_row(const float4* __restrict__ x1,
                                                 const float4* __restrict__ x2,
                                                 int ub, int c) {
    return (c < ub) ? (x1 + (size_t)c * NV4) : (x2 + (size_t)(c - ub) * NV4);
}

template<bool FIRST, bool WRITE_CUR>
__global__ void spmm_gather_kernel(const int* __restrict__ rptr,
                                   const int* __restrict__ scol,
                                   const float* __restrict__ sval,
                                   const float4* __restrict__ x1,
                                   const float4* __restrict__ x2,
                                   int ubound,
                                   float4* __restrict__ cur,
                                   float4* __restrict__ acc,
                                   int n_rows) {
    int t = blockIdx.x * blockDim.x + threadIdx.x;
    int r   = t >> 5;
    int sub = t & 31;
    if (r >= n_rows) return;

    int e0 = rptr[r];
    int e1 = rptr[r + 1];

    float4 a0 = make_float4(0.f, 0.f, 0.f, 0.f);
    float4 a1 = make_float4(0.f, 0.f, 0.f, 0.f);

    int e = e0;
    for (; e + 2 <= e1; e += 2) {
        int   c0 = scol[e];
        int   c1 = scol[e + 1];
        float v0 = sval[e];
        float v1 = sval[e + 1];
        const float4* p0 = FIRST ? sel_row(x1, x2, ubound, c0)
                                 : (x1 + (size_t)c0 * NV4);
        const float4* p1 = FIRST ? sel_row(x1, x2, ubound, c1)
                                 : (x1 + (size_t)c1 * NV4);
        float4 xv0 = p0[sub];                 // independent gathers -> 2x MLP
        float4 xv1 = p1[sub];
        a0.x += v0 * xv0.x; a0.y += v0 * xv0.y; a0.z += v0 * xv0.z; a0.w += v0 * xv0.w;
        a1.x += v1 * xv1.x; a1.y += v1 * xv1.y; a1.z += v1 * xv1.z; a1.w += v1 * xv1.w;
    }
    if (e < e1) {
        int   c0 = scol[e];
        float v0 = sval[e];
        const float4* p0 = FIRST ? sel_row(x1, x2, ubound, c0)
                                 : (x1 + (size_t)c0 * NV4);
        float4 xv0 = p0[sub];
        a0.x += v0 * xv0.x; a0.y += v0 * xv0.y; a0.z += v0 * xv0.z; a0.w += v0 * xv0.w;
    }
    float4 a = make_float4(a0.x + a1.x, a0.y + a1.y, a0.z + a1.z, a0.w + a1.w);

    size_t o = (size_t)r * NV4 + sub;
    if (WRITE_CUR) cur[o] = a;

    float4 ac;
    if (FIRST) {
        ac = sel_row(x1, x2, ubound, r)[sub];  // acc = e0[r] + a  (streaming read)
    } else {
        ac = acc[o];
    }
    ac.x += a.x; ac.y += a.y; ac.z += a.z; ac.w += a.w;
    acc[o] = ac;
}

// ---------------------------------------------------------------------------
extern "C" void kernel_launch(void* const* d_in, const int* in_sizes, int n_in,
                              void* d_out, int out_size, void* d_ws, size_t ws_size,
                              hipStream_t stream) {
    const float* uE    = (const float*)d_in[0];
    const float* iE    = (const float*)d_in[1];
    const int*   arows = (const int*)  d_in[2];
    const int*   acols = (const int*)  d_in[3];
    const float* avals = (const float*)d_in[4];
    const int*   urows = (const int*)  d_in[5];
    const int*   ucols = (const int*)  d_in[6];
    const float* uvals = (const float*)d_in[7];

    float* acc  = (float*)d_out;                              // N_TOTAL x 128
    float* uacc = acc + (size_t)N_TOTAL * LATDIM;             // USER_N x 128

    float* A    = (float*)d_ws;                               // N_TOTAL*128
    float* B    = A + (size_t)N_TOTAL * LATDIM;               // N_TOTAL*128
    int*   cnt  = (int*)(B + (size_t)N_TOTAL * LATDIM);       // N_TOTAL
    int*   rptr = cnt + N_TOTAL;                              // N_TOTAL+1
    int*   curp = rptr + N_TOTAL + 1;                         // N_TOTAL
    int*   bsum = curp + N_TOTAL;                             // 4096
    int*   scol = bsum + 4096;                                // N_EDGES
    float* sval = (float*)(scol + N_EDGES_C);                 // N_EDGES

    const int TB = 256;

    // ================= main graph CSR =================
    hipMemsetAsync(cnt, 0, N_TOTAL * sizeof(int), stream);
    hist_kernel<<<(N_EDGES_C + TB - 1) / TB, TB, 0, stream>>>(arows, cnt, N_EDGES_C);
    {
        int nb = (N_TOTAL + SCAN_B - 1) / SCAN_B;
        scan_block_kernel<<<nb, SCAN_B, 0, stream>>>(cnt, rptr, bsum, N_TOTAL);
        scan_bsum_kernel<<<1, SCAN_B, 0, stream>>>(bsum, nb);
        scan_add_kernel<<<(N_TOTAL + TB - 1) / TB, TB, 0, stream>>>(
            rptr, bsum, curp, N_TOTAL, N_EDGES_C);
    }
    scatter_kernel<<<(N_EDGES_C + TB - 1) / TB, TB, 0, stream>>>(
        arows, acols, avals, curp, scol, sval, N_EDGES_C);

    // ================= main graph layers =================
    {
        int threads = N_TOTAL * 32;
        int grid = (threads + TB - 1) / TB;
        // L1: gather from concat(uE,iE); acc = e0 + cur; write cur->B
        spmm_gather_kernel<true, true><<<grid, TB, 0, stream>>>(
            rptr, scol, sval, (const float4*)uE, (const float4*)iE, USER_N,
            (float4*)B, (float4*)acc, N_TOTAL);
        // L2: gather from B; acc += cur; write cur->A
        spmm_gather_kernel<false, true><<<grid, TB, 0, stream>>>(
            rptr, scol, sval, (const float4*)B, nullptr, 0,
            (float4*)A, (float4*)acc, N_TOTAL);
        // L3: gather from A; acc += cur; no cur write
        spmm_gather_kernel<false, false><<<grid, TB, 0, stream>>>(
            rptr, scol, sval, (const float4*)A, nullptr, 0,
            (float4*)B, (float4*)acc, N_TOTAL);
    }

    // ================= user-user graph CSR =================
    hipMemsetAsync(cnt, 0, USER_N * sizeof(int), stream);
    hist_kernel<<<(UU_EDGES_C + TB - 1) / TB, TB, 0, stream>>>(urows, cnt, UU_EDGES_C);
    {
        int nb = (USER_N + SCAN_B - 1) / SCAN_B;
        scan_block_kernel<<<nb, SCAN_B, 0, stream>>>(cnt, rptr, bsum, USER_N);
        scan_bsum_kernel<<<1, SCAN_B, 0, stream>>>(bsum, nb);
        scan_add_kernel<<<(USER_N + TB - 1) / TB, TB, 0, stream>>>(
            rptr, bsum, curp, USER_N, UU_EDGES_C);
    }
    scatter_kernel<<<(UU_EDGES_C + TB - 1) / TB, TB, 0, stream>>>(
        urows, ucols, uvals, curp, scol, sval, UU_EDGES_C);

    // ================= user-user layers =================
    {
        int threads = USER_N * 32;
        int grid = (threads + TB - 1) / TB;
        // L1: gather from uE (all cols < USER_N); uacc = uE + cur; write cur->A
        spmm_gather_kernel<true, true><<<grid, TB, 0, stream>>>(
            rptr, scol, sval, (const float4*)uE, (const float4*)uE, USER_N,
            (float4*)A, (float4*)uacc, USER_N);
        // L2: gather from A; uacc += cur; no cur write
        spmm_gather_kernel<false, false><<<grid, TB, 0, stream>>>(
            rptr, scol, sval, (const float4*)A, nullptr, 0,
            (float4*)B, (float4*)uacc, USER_N);
    }
}

// Round 4
// 421.551 us; speedup vs baseline: 5.6138x; 1.3957x over previous
//
#include <hip/hip_runtime.h>
#include <hip/hip_fp16.h>

#define USER_N   100000
#define ITEM_N   200000
#define LATDIM   128
#define NV4      32                     // float4 per row
#define N_TOTAL  300000                 // user+item rows (main graph)
#define NR_ALL   400000                 // + user-graph rows appended
#define N_EDGES_C  600000
#define UU_EDGES_C 300000
#define NE_ALL   900000
#define SCAN_B   256

// 8-byte fp16 quad (4 dims per lane, 32 lanes per 128-dim row)
struct alignas(8) h4 { __half2 lo, hi; };

__device__ __forceinline__ h4 to_h4(float4 a) {
    h4 r; r.lo = __floats2half2_rn(a.x, a.y); r.hi = __floats2half2_rn(a.z, a.w);
    return r;
}
__device__ __forceinline__ float4 to_f4(h4 h) {
    float2 l = __half22float2(h.lo), hh = __half22float2(h.hi);
    return make_float4(l.x, l.y, hh.x, hh.y);
}
__device__ __forceinline__ void fma4(float4& a, float v, float4 x) {
    a.x += v * x.x; a.y += v * x.y; a.z += v * x.z; a.w += v * x.w;
}

// ---------------------------------------------------------------------------
// Combined CSR build over NR_ALL rows / NE_ALL edges.
// Main edges: rows/cols as-is. User edges: rows += N_TOTAL, cols += N_TOTAL.
// ---------------------------------------------------------------------------
__global__ void hist2_kernel(const int* __restrict__ ar, const int* __restrict__ ur,
                             int* __restrict__ cnt) {
    int i = blockIdx.x * blockDim.x + threadIdx.x;
    if (i < N_EDGES_C)      atomicAdd(&cnt[ar[i]], 1);
    else if (i < NE_ALL)    atomicAdd(&cnt[ur[i - N_EDGES_C] + N_TOTAL], 1);
}

__global__ void scan_block_kernel(const int* __restrict__ cnt,
                                  int* __restrict__ rptr,
                                  int* __restrict__ bsum, int n) {
    __shared__ int s[SCAN_B];
    int i = blockIdx.x * SCAN_B + threadIdx.x;
    int v = (i < n) ? cnt[i] : 0;
    s[threadIdx.x] = v;
    __syncthreads();
    for (int off = 1; off < SCAN_B; off <<= 1) {
        int t = (threadIdx.x >= off) ? s[threadIdx.x - off] : 0;
        __syncthreads();
        s[threadIdx.x] += t;
        __syncthreads();
    }
    if (i < n) rptr[i] = s[threadIdx.x] - v;
    if (threadIdx.x == SCAN_B - 1) bsum[blockIdx.x] = s[threadIdx.x];
}

__global__ void scan_bsum_kernel(int* __restrict__ bsum, int nb) {
    __shared__ int s[SCAN_B];
    __shared__ int carry;
    if (threadIdx.x == 0) carry = 0;
    __syncthreads();
    for (int base = 0; base < nb; base += SCAN_B) {
        int i = base + threadIdx.x;
        int v = (i < nb) ? bsum[i] : 0;
        s[threadIdx.x] = v;
        __syncthreads();
        for (int off = 1; off < SCAN_B; off <<= 1) {
            int t = (threadIdx.x >= off) ? s[threadIdx.x - off] : 0;
            __syncthreads();
            s[threadIdx.x] += t;
            __syncthreads();
        }
        if (i < nb) bsum[i] = s[threadIdx.x] - v + carry;
        __syncthreads();
        if (threadIdx.x == 0) carry += s[SCAN_B - 1];
        __syncthreads();
    }
}

__global__ void scan_add_kernel(int* __restrict__ rptr, const int* __restrict__ bsum,
                                int* __restrict__ cursor, int n, int n_edges) {
    int i = blockIdx.x * blockDim.x + threadIdx.x;
    if (i < n) {
        int v = rptr[i] + bsum[i / SCAN_B];
        rptr[i]   = v;
        cursor[i] = v;
    }
    if (i == 0) rptr[n] = n_edges;
}

__global__ void scatter2_kernel(const int* __restrict__ ar, const int* __restrict__ ac,
                                const float* __restrict__ av,
                                const int* __restrict__ ur, const int* __restrict__ uc,
                                const float* __restrict__ uv,
                                int* __restrict__ cursor,
                                int* __restrict__ scol, float* __restrict__ sval) {
    int i = blockIdx.x * blockDim.x + threadIdx.x;
    int r, c; float v;
    if (i < N_EDGES_C)      { r = ar[i];             c = ac[i];                      v = av[i]; }
    else if (i < NE_ALL)    { int j = i - N_EDGES_C; r = ur[j] + N_TOTAL; c = uc[j] + N_TOTAL; v = uv[j]; }
    else return;
    int pos = atomicAdd(&cursor[r], 1);
    scol[pos] = c;
    sval[pos] = v;
}

// ---------------------------------------------------------------------------
// Pass 1: gather from f32 inputs; write l1 as fp16. Rows 0..NR_ALL.
//   col c: c<USER_N -> uE[c]; c<N_TOTAL -> iE[c-USER_N]; else -> uE[c-N_TOTAL]
// ---------------------------------------------------------------------------
__global__ void spmm_pass1(const int* __restrict__ rptr,
                           const int* __restrict__ scol,
                           const float* __restrict__ sval,
                           const float4* __restrict__ uE,
                           const float4* __restrict__ iE,
                           h4* __restrict__ cur1) {
    int t = blockIdx.x * blockDim.x + threadIdx.x;
    int r = t >> 5, sub = t & 31;
    if (r >= NR_ALL) return;
    int e0 = rptr[r], e1 = rptr[r + 1];

    float4 a0 = make_float4(0.f,0.f,0.f,0.f), a1 = a0;
    int e = e0;
    for (; e + 2 <= e1; e += 2) {
        int c0 = scol[e], c1 = scol[e + 1];
        float v0 = sval[e], v1 = sval[e + 1];
        const float4* p0 = (c0 < USER_N) ? uE + (size_t)c0 * NV4
                         : (c0 < N_TOTAL) ? iE + (size_t)(c0 - USER_N) * NV4
                                          : uE + (size_t)(c0 - N_TOTAL) * NV4;
        const float4* p1 = (c1 < USER_N) ? uE + (size_t)c1 * NV4
                         : (c1 < N_TOTAL) ? iE + (size_t)(c1 - USER_N) * NV4
                                          : uE + (size_t)(c1 - N_TOTAL) * NV4;
        float4 x0 = p0[sub], x1 = p1[sub];
        fma4(a0, v0, x0); fma4(a1, v1, x1);
    }
    if (e < e1) {
        int c0 = scol[e]; float v0 = sval[e];
        const float4* p0 = (c0 < USER_N) ? uE + (size_t)c0 * NV4
                         : (c0 < N_TOTAL) ? iE + (size_t)(c0 - USER_N) * NV4
                                          : uE + (size_t)(c0 - N_TOTAL) * NV4;
        fma4(a0, v0, p0[sub]);
    }
    float4 a = make_float4(a0.x+a1.x, a0.y+a1.y, a0.z+a1.z, a0.w+a1.w);
    cur1[(size_t)r * NV4 + sub] = to_h4(a);
}

// ---------------------------------------------------------------------------
// Pass 2: gather l2 from cur1 (fp16). Main rows: write cur2 fp16.
// User rows (r>=N_TOTAL): finish uacc = u0 + ul1 + ul2 (f32 write).
// ---------------------------------------------------------------------------
__global__ void spmm_pass2(const int* __restrict__ rptr,
                           const int* __restrict__ scol,
                           const float* __restrict__ sval,
                           const h4* __restrict__ cur1,
                           const float4* __restrict__ uE,
                           h4* __restrict__ cur2,
                           float4* __restrict__ uacc) {
    int t = blockIdx.x * blockDim.x + threadIdx.x;
    int r = t >> 5, sub = t & 31;
    if (r >= NR_ALL) return;
    int e0 = rptr[r], e1 = rptr[r + 1];

    float4 a0 = make_float4(0.f,0.f,0.f,0.f), a1 = a0;
    int e = e0;
    for (; e + 2 <= e1; e += 2) {
        int c0 = scol[e], c1 = scol[e + 1];
        float v0 = sval[e], v1 = sval[e + 1];
        h4 h0 = cur1[(size_t)c0 * NV4 + sub];
        h4 h1 = cur1[(size_t)c1 * NV4 + sub];
        fma4(a0, v0, to_f4(h0)); fma4(a1, v1, to_f4(h1));
    }
    if (e < e1) {
        int c0 = scol[e]; float v0 = sval[e];
        fma4(a0, v0, to_f4(cur1[(size_t)c0 * NV4 + sub]));
    }
    float4 a = make_float4(a0.x+a1.x, a0.y+a1.y, a0.z+a1.z, a0.w+a1.w);

    size_t o = (size_t)r * NV4 + sub;
    if (r < N_TOTAL) {
        cur2[o] = to_h4(a);
    } else {
        int ur = r - N_TOTAL;
        float4 u0 = uE[(size_t)ur * NV4 + sub];
        float4 l1 = to_f4(cur1[o]);
        uacc[(size_t)ur * NV4 + sub] =
            make_float4(u0.x + l1.x + a.x, u0.y + l1.y + a.y,
                        u0.z + l1.z + a.z, u0.w + l1.w + a.w);
    }
}

// ---------------------------------------------------------------------------
// Pass 3 (main rows only): l3 = gather from cur2; acc = e0 + l1 + l2 + l3.
// ---------------------------------------------------------------------------
__global__ void spmm_pass3(const int* __restrict__ rptr,
                           const int* __restrict__ scol,
                           const float* __restrict__ sval,
                           const h4* __restrict__ cur2,
                           const h4* __restrict__ cur1,
                           const float4* __restrict__ uE,
                           const float4* __restrict__ iE,
                           float4* __restrict__ acc) {
    int t = blockIdx.x * blockDim.x + threadIdx.x;
    int r = t >> 5, sub = t & 31;
    if (r >= N_TOTAL) return;
    int e0 = rptr[r], e1 = rptr[r + 1];

    float4 a0 = make_float4(0.f,0.f,0.f,0.f), a1 = a0;
    int e = e0;
    for (; e + 2 <= e1; e += 2) {
        int c0 = scol[e], c1 = scol[e + 1];
        float v0 = sval[e], v1 = sval[e + 1];
        h4 h0 = cur2[(size_t)c0 * NV4 + sub];
        h4 h1 = cur2[(size_t)c1 * NV4 + sub];
        fma4(a0, v0, to_f4(h0)); fma4(a1, v1, to_f4(h1));
    }
    if (e < e1) {
        int c0 = scol[e]; float v0 = sval[e];
        fma4(a0, v0, to_f4(cur2[(size_t)c0 * NV4 + sub]));
    }
    float4 a = make_float4(a0.x+a1.x, a0.y+a1.y, a0.z+a1.z, a0.w+a1.w);

    size_t o = (size_t)r * NV4 + sub;
    float4 ez = (r < USER_N) ? uE[(size_t)r * NV4 + sub]
                             : iE[(size_t)(r - USER_N) * NV4 + sub];
    float4 l1 = to_f4(cur1[o]);
    float4 l2 = to_f4(cur2[o]);
    acc[o] = make_float4(ez.x + l1.x + l2.x + a.x,
                         ez.y + l1.y + l2.y + a.y,
                         ez.z + l1.z + l2.z + a.z,
                         ez.w + l1.w + l2.w + a.w);
}

// ---------------------------------------------------------------------------
extern "C" void kernel_launch(void* const* d_in, const int* in_sizes, int n_in,
                              void* d_out, int out_size, void* d_ws, size_t ws_size,
                              hipStream_t stream) {
    const float* uE    = (const float*)d_in[0];
    const float* iE    = (const float*)d_in[1];
    const int*   arows = (const int*)  d_in[2];
    const int*   acols = (const int*)  d_in[3];
    const float* avals = (const float*)d_in[4];
    const int*   urows = (const int*)  d_in[5];
    const int*   ucols = (const int*)  d_in[6];
    const float* uvals = (const float*)d_in[7];

    float* acc  = (float*)d_out;                              // N_TOTAL x 128 f32
    float* uacc = acc + (size_t)N_TOTAL * LATDIM;             // USER_N x 128 f32

    // workspace layout
    h4*    cur1 = (h4*)d_ws;                                  // NR_ALL*32 h4 (102.4 MB)
    h4*    cur2 = cur1 + (size_t)NR_ALL * NV4;                // NR_ALL*32 h4 (102.4 MB)
    int*   cnt  = (int*)(cur2 + (size_t)NR_ALL * NV4);        // NR_ALL
    int*   rptr = cnt + NR_ALL;                               // NR_ALL+1
    int*   curp = rptr + NR_ALL + 1;                          // NR_ALL
    int*   bsum = curp + NR_ALL;                              // 4096
    int*   scol = bsum + 4096;                                // NE_ALL
    float* sval = (float*)(scol + NE_ALL);                    // NE_ALL

    const int TB = 256;

    // ---- combined CSR build ----
    hipMemsetAsync(cnt, 0, NR_ALL * sizeof(int), stream);
    hist2_kernel<<<(NE_ALL + TB - 1) / TB, TB, 0, stream>>>(arows, urows, cnt);
    {
        int nb = (NR_ALL + SCAN_B - 1) / SCAN_B;
        scan_block_kernel<<<nb, SCAN_B, 0, stream>>>(cnt, rptr, bsum, NR_ALL);
        scan_bsum_kernel<<<1, SCAN_B, 0, stream>>>(bsum, nb);
        scan_add_kernel<<<(NR_ALL + TB - 1) / TB, TB, 0, stream>>>(
            rptr, bsum, curp, NR_ALL, NE_ALL);
    }
    scatter2_kernel<<<(NE_ALL + TB - 1) / TB, TB, 0, stream>>>(
        arows, acols, avals, urows, ucols, uvals, curp, scol, sval);

    // ---- three fused passes ----
    {
        int threads = NR_ALL * 32;
        int grid = (threads + TB - 1) / TB;
        spmm_pass1<<<grid, TB, 0, stream>>>(
            rptr, scol, sval, (const float4*)uE, (const float4*)iE, cur1);
        spmm_pass2<<<grid, TB, 0, stream>>>(
            rptr, scol, sval, cur1, (const float4*)uE, cur2, (float4*)uacc);
    }
    {
        int threads = N_TOTAL * 32;
        int grid = (threads + TB - 1) / TB;
        spmm_pass3<<<grid, TB, 0, stream>>>(
            rptr, scol, sval, cur2, cur1,
            (const float4*)uE, (const float4*)iE, (float4*)acc);
    }
}

// Round 5
// 382.033 us; speedup vs baseline: 6.1945x; 1.1034x over previous
//
#include <hip/hip_runtime.h>
#include <hip/hip_fp16.h>

#define USER_N   100000
#define ITEM_N   200000
#define LATDIM   128
#define NV4      32                     // 4-dim quads per row
#define N_TOTAL  300000                 // user+item rows (main graph)
#define NR_ALL   400000                 // + user-graph rows appended
#define N_EDGES_C  600000
#define UU_EDGES_C 300000
#define NE_ALL   900000
#define SCAN_B   256

// 8-byte fp16 quad (4 dims/lane, 32 lanes per 128-dim row)
struct alignas(8) h4 { __half2 lo, hi; };

typedef float f4_ext __attribute__((ext_vector_type(4)));

__device__ __forceinline__ h4 to_h4(float4 a) {
    h4 r; r.lo = __floats2half2_rn(a.x, a.y); r.hi = __floats2half2_rn(a.z, a.w);
    return r;
}
__device__ __forceinline__ float4 to_f4(h4 h) {
    float2 l = __half22float2(h.lo), hh = __half22float2(h.hi);
    return make_float4(l.x, l.y, hh.x, hh.y);
}
__device__ __forceinline__ void fma4(float4& a, float v, float4 x) {
    a.x += v * x.x; a.y += v * x.y; a.z += v * x.z; a.w += v * x.w;
}
__device__ __forceinline__ float4 nt_load4(const float4* p) {
    f4_ext v = __builtin_nontemporal_load((const f4_ext*)p);
    return make_float4(v.x, v.y, v.z, v.w);
}
__device__ __forceinline__ void nt_store4(float4* p, float4 a) {
    f4_ext v = {a.x, a.y, a.z, a.w};
    __builtin_nontemporal_store(v, (f4_ext*)p);
}

// ---------------------------------------------------------------------------
// CSR build over NR_ALL rows / NE_ALL edges.
// Main edges: as-is. User edges: row += N_TOTAL, col += N_TOTAL.
// ---------------------------------------------------------------------------
__global__ void hist2_kernel(const int* __restrict__ ar, const int* __restrict__ ur,
                             int* __restrict__ cnt) {
    int i = blockIdx.x * blockDim.x + threadIdx.x;
    if (i < N_EDGES_C)      atomicAdd(&cnt[ar[i]], 1);
    else if (i < NE_ALL)    atomicAdd(&cnt[ur[i - N_EDGES_C] + N_TOTAL], 1);
}

__global__ void scan_block_kernel(const int* __restrict__ cnt,
                                  int* __restrict__ rptr,
                                  int* __restrict__ bsum, int n) {
    __shared__ int s[SCAN_B];
    int i = blockIdx.x * SCAN_B + threadIdx.x;
    int v = (i < n) ? cnt[i] : 0;
    s[threadIdx.x] = v;
    __syncthreads();
    for (int off = 1; off < SCAN_B; off <<= 1) {
        int t = (threadIdx.x >= off) ? s[threadIdx.x - off] : 0;
        __syncthreads();
        s[threadIdx.x] += t;
        __syncthreads();
    }
    if (i < n) rptr[i] = s[threadIdx.x] - v;
    if (threadIdx.x == SCAN_B - 1) bsum[blockIdx.x] = s[threadIdx.x];
}

__global__ void scan_bsum_kernel(int* __restrict__ bsum, int nb) {
    __shared__ int s[SCAN_B];
    __shared__ int carry;
    if (threadIdx.x == 0) carry = 0;
    __syncthreads();
    for (int base = 0; base < nb; base += SCAN_B) {
        int i = base + threadIdx.x;
        int v = (i < nb) ? bsum[i] : 0;
        s[threadIdx.x] = v;
        __syncthreads();
        for (int off = 1; off < SCAN_B; off <<= 1) {
            int t = (threadIdx.x >= off) ? s[threadIdx.x - off] : 0;
            __syncthreads();
            s[threadIdx.x] += t;
            __syncthreads();
        }
        if (i < nb) bsum[i] = s[threadIdx.x] - v + carry;
        __syncthreads();
        if (threadIdx.x == 0) carry += s[SCAN_B - 1];
        __syncthreads();
    }
}

__global__ void scan_add_kernel(int* __restrict__ rptr, const int* __restrict__ bsum,
                                int* __restrict__ cursor, int n, int n_edges) {
    int i = blockIdx.x * blockDim.x + threadIdx.x;
    if (i < n) {
        int v = rptr[i] + bsum[i / SCAN_B];
        rptr[i]   = v;
        cursor[i] = v;
    }
    if (i == 0) rptr[n] = n_edges;
}

__global__ void scatter2_kernel(const int* __restrict__ ar, const int* __restrict__ ac,
                                const float* __restrict__ av,
                                const int* __restrict__ ur, const int* __restrict__ uc,
                                const float* __restrict__ uv,
                                int* __restrict__ cursor,
                                int* __restrict__ scol, float* __restrict__ sval) {
    int i = blockIdx.x * blockDim.x + threadIdx.x;
    int r, c; float v;
    if (i < N_EDGES_C)      { r = ar[i];             c = ac[i];           v = av[i]; }
    else if (i < NE_ALL)    { int j = i - N_EDGES_C; r = ur[j] + N_TOTAL; c = uc[j] + N_TOTAL; v = uv[j]; }
    else return;
    int pos = atomicAdd(&cursor[r], 1);
    scol[pos] = c;
    sval[pos] = v;
}

// ---------------------------------------------------------------------------
// pass0: E16 = fp16(concat(uE, iE))  — one streaming conversion.
// nt-loads: f32 inputs are never read again.
// ---------------------------------------------------------------------------
__global__ void conv_kernel(const float4* __restrict__ uE,
                            const float4* __restrict__ iE,
                            h4* __restrict__ E16) {
    int i = blockIdx.x * blockDim.x + threadIdx.x;   // element index over N_TOTAL*NV4
    if (i >= N_TOTAL * NV4) return;
    const int ub = USER_N * NV4;
    float4 v = (i < ub) ? nt_load4(uE + i) : nt_load4(iE + (i - ub));
    E16[i] = to_h4(v);
}

// col c -> row in E16 (user-graph cols are shifted by N_TOTAL)
__device__ __forceinline__ int e16_row(int c) {
    return (c < N_TOTAL) ? c : c - N_TOTAL;
}

// ---------------------------------------------------------------------------
// pass1: l1 = A * e0, gathering fp16 rows from E16 (77 MB, L3-resident).
// ---------------------------------------------------------------------------
__global__ void spmm_pass1(const int* __restrict__ rptr,
                           const int* __restrict__ scol,
                           const float* __restrict__ sval,
                           const h4* __restrict__ E16,
                           h4* __restrict__ cur1) {
    int t = blockIdx.x * blockDim.x + threadIdx.x;
    int r = t >> 5, sub = t & 31;
    if (r >= NR_ALL) return;
    int e0 = rptr[r], e1 = rptr[r + 1];

    float4 a0 = make_float4(0.f,0.f,0.f,0.f), a1 = a0;
    int e = e0;
    for (; e + 2 <= e1; e += 2) {
        int c0 = scol[e], c1 = scol[e + 1];
        float v0 = sval[e], v1 = sval[e + 1];
        h4 h0 = E16[(size_t)e16_row(c0) * NV4 + sub];
        h4 h1 = E16[(size_t)e16_row(c1) * NV4 + sub];
        fma4(a0, v0, to_f4(h0)); fma4(a1, v1, to_f4(h1));
    }
    if (e < e1) {
        int c0 = scol[e]; float v0 = sval[e];
        fma4(a0, v0, to_f4(E16[(size_t)e16_row(c0) * NV4 + sub]));
    }
    float4 a = make_float4(a0.x+a1.x, a0.y+a1.y, a0.z+a1.z, a0.w+a1.w);
    cur1[(size_t)r * NV4 + sub] = to_h4(a);
}

// ---------------------------------------------------------------------------
// pass2: l2 = A * l1 (gather cur1).
// Main rows: write cur2. User rows: uacc = e16 + l1 + l2 (nt f32 write).
// ---------------------------------------------------------------------------
__global__ void spmm_pass2(const int* __restrict__ rptr,
                           const int* __restrict__ scol,
                           const float* __restrict__ sval,
                           const h4* __restrict__ cur1,
                           const h4* __restrict__ E16,
                           h4* __restrict__ cur2,
                           float4* __restrict__ uacc) {
    int t = blockIdx.x * blockDim.x + threadIdx.x;
    int r = t >> 5, sub = t & 31;
    if (r >= NR_ALL) return;
    int e0 = rptr[r], e1 = rptr[r + 1];

    float4 a0 = make_float4(0.f,0.f,0.f,0.f), a1 = a0;
    int e = e0;
    for (; e + 2 <= e1; e += 2) {
        int c0 = scol[e], c1 = scol[e + 1];
        float v0 = sval[e], v1 = sval[e + 1];
        h4 h0 = cur1[(size_t)c0 * NV4 + sub];
        h4 h1 = cur1[(size_t)c1 * NV4 + sub];
        fma4(a0, v0, to_f4(h0)); fma4(a1, v1, to_f4(h1));
    }
    if (e < e1) {
        int c0 = scol[e]; float v0 = sval[e];
        fma4(a0, v0, to_f4(cur1[(size_t)c0 * NV4 + sub]));
    }
    float4 a = make_float4(a0.x+a1.x, a0.y+a1.y, a0.z+a1.z, a0.w+a1.w);

    size_t o = (size_t)r * NV4 + sub;
    if (r < N_TOTAL) {
        cur2[o] = to_h4(a);
    } else {
        int ur = r - N_TOTAL;
        float4 u0 = to_f4(E16[(size_t)ur * NV4 + sub]);
        float4 l1 = to_f4(cur1[o]);
        nt_store4(uacc + (size_t)ur * NV4 + sub,
                  make_float4(u0.x + l1.x + a.x, u0.y + l1.y + a.y,
                              u0.z + l1.z + a.z, u0.w + l1.w + a.w));
    }
}

// ---------------------------------------------------------------------------
// pass3 (main rows): l3 = A * l2; acc = e16 + l1 + l2 + l3 (nt f32 write).
// ---------------------------------------------------------------------------
__global__ void spmm_pass3(const int* __restrict__ rptr,
                           const int* __restrict__ scol,
                           const float* __restrict__ sval,
                           const h4* __restrict__ cur2,
                           const h4* __restrict__ cur1,
                           const h4* __restrict__ E16,
                           float4* __restrict__ acc) {
    int t = blockIdx.x * blockDim.x + threadIdx.x;
    int r = t >> 5, sub = t & 31;
    if (r >= N_TOTAL) return;
    int e0 = rptr[r], e1 = rptr[r + 1];

    float4 a0 = make_float4(0.f,0.f,0.f,0.f), a1 = a0;
    int e = e0;
    for (; e + 2 <= e1; e += 2) {
        int c0 = scol[e], c1 = scol[e + 1];
        float v0 = sval[e], v1 = sval[e + 1];
        h4 h0 = cur2[(size_t)c0 * NV4 + sub];
        h4 h1 = cur2[(size_t)c1 * NV4 + sub];
        fma4(a0, v0, to_f4(h0)); fma4(a1, v1, to_f4(h1));
    }
    if (e < e1) {
        int c0 = scol[e]; float v0 = sval[e];
        fma4(a0, v0, to_f4(cur2[(size_t)c0 * NV4 + sub]));
    }
    float4 a = make_float4(a0.x+a1.x, a0.y+a1.y, a0.z+a1.z, a0.w+a1.w);

    size_t o = (size_t)r * NV4 + sub;
    float4 ez = to_f4(E16[o]);
    float4 l1 = to_f4(cur1[o]);
    float4 l2 = to_f4(cur2[o]);
    nt_store4(acc + o,
              make_float4(ez.x + l1.x + l2.x + a.x,
                          ez.y + l1.y + l2.y + a.y,
                          ez.z + l1.z + l2.z + a.z,
                          ez.w + l1.w + l2.w + a.w));
}

// ---------------------------------------------------------------------------
extern "C" void kernel_launch(void* const* d_in, const int* in_sizes, int n_in,
                              void* d_out, int out_size, void* d_ws, size_t ws_size,
                              hipStream_t stream) {
    const float* uE    = (const float*)d_in[0];
    const float* iE    = (const float*)d_in[1];
    const int*   arows = (const int*)  d_in[2];
    const int*   acols = (const int*)  d_in[3];
    const float* avals = (const float*)d_in[4];
    const int*   urows = (const int*)  d_in[5];
    const int*   ucols = (const int*)  d_in[6];
    const float* uvals = (const float*)d_in[7];

    float* acc  = (float*)d_out;                              // N_TOTAL x 128 f32
    float* uacc = acc + (size_t)N_TOTAL * LATDIM;             // USER_N x 128 f32

    // workspace layout
    h4*    E16  = (h4*)d_ws;                                  // N_TOTAL*NV4  (76.8 MB)
    h4*    cur1 = E16 + (size_t)N_TOTAL * NV4;                // NR_ALL*NV4   (102.4 MB)
    h4*    cur2 = cur1 + (size_t)NR_ALL * NV4;                // N_TOTAL*NV4  (76.8 MB)
    int*   cnt  = (int*)(cur2 + (size_t)N_TOTAL * NV4);       // NR_ALL
    int*   rptr = cnt + NR_ALL;                               // NR_ALL+1
    int*   curp = rptr + NR_ALL + 1;                          // NR_ALL
    int*   bsum = curp + NR_ALL;                              // 4096
    int*   scol = bsum + 4096;                                // NE_ALL
    float* sval = (float*)(scol + NE_ALL);                    // NE_ALL

    const int TB = 256;

    // ---- CSR build (small traffic; run before conv so E16 stays hot) ----
    hipMemsetAsync(cnt, 0, NR_ALL * sizeof(int), stream);
    hist2_kernel<<<(NE_ALL + TB - 1) / TB, TB, 0, stream>>>(arows, urows, cnt);
    {
        int nb = (NR_ALL + SCAN_B - 1) / SCAN_B;
        scan_block_kernel<<<nb, SCAN_B, 0, stream>>>(cnt, rptr, bsum, NR_ALL);
        scan_bsum_kernel<<<1, SCAN_B, 0, stream>>>(bsum, nb);
        scan_add_kernel<<<(NR_ALL + TB - 1) / TB, TB, 0, stream>>>(
            rptr, bsum, curp, NR_ALL, NE_ALL);
    }
    scatter2_kernel<<<(NE_ALL + TB - 1) / TB, TB, 0, stream>>>(
        arows, acols, avals, urows, ucols, uvals, curp, scol, sval);

    // ---- pass0: fp16 conversion of inputs ----
    conv_kernel<<<(N_TOTAL * NV4 + TB - 1) / TB, TB, 0, stream>>>(
        (const float4*)uE, (const float4*)iE, E16);

    // ---- three fused SpMM passes ----
    {
        int threads = NR_ALL * 32;
        int grid = (threads + TB - 1) / TB;
        spmm_pass1<<<grid, TB, 0, stream>>>(rptr, scol, sval, E16, cur1);
        spmm_pass2<<<grid, TB, 0, stream>>>(rptr, scol, sval, cur1, E16,
                                            cur2, (float4*)uacc);
    }
    {
        int threads = N_TOTAL * 32;
        int grid = (threads + TB - 1) / TB;
        spmm_pass3<<<grid, TB, 0, stream>>>(rptr, scol, sval, cur2, cur1, E16,
                                            (float4*)acc);
    }
}

// Round 6
// 352.814 us; speedup vs baseline: 6.7075x; 1.0828x over previous
//
#include <hip/hip_runtime.h>
#include <hip/hip_fp16.h>

#define USER_N   100000
#define ITEM_N   200000
#define LATDIM   128
#define NV4      32                     // float4 per row (f32 rows)
#define NV8      16                     // h8 per row (fp16 rows)
#define N_TOTAL  300000
#define NR_ALL   400000                 // + user-graph rows appended
#define N_EDGES_C  600000
#define UU_EDGES_C 300000
#define NE_ALL   900000
#define SCAN_B   256
#define CONV_T   (N_TOTAL * NV8)        // conv threads in fused kernel

// 16-byte fp16 oct (8 dims/lane, 16 lanes per 128-dim row)
struct alignas(16) h8 { __half2 a, b, c, d; };
struct alignas(8)  Edge { int c; float v; };

typedef float f4_ext __attribute__((ext_vector_type(4)));
typedef int   i4_ext __attribute__((ext_vector_type(4)));
typedef int   i2_ext __attribute__((ext_vector_type(2)));

union H8I { i4_ext i; h8 h; };
union EDI { i2_ext i; Edge e; };

__device__ __forceinline__ float4 nt_load4(const float4* p) {
    f4_ext v = __builtin_nontemporal_load((const f4_ext*)p);
    return make_float4(v.x, v.y, v.z, v.w);
}
__device__ __forceinline__ void nt_store4(float4* p, float4 a) {
    f4_ext v = {a.x, a.y, a.z, a.w};
    __builtin_nontemporal_store(v, (f4_ext*)p);
}
__device__ __forceinline__ h8 nt_load_h8(const h8* p) {
    H8I u; u.i = __builtin_nontemporal_load((const i4_ext*)p);
    return u.h;
}
__device__ __forceinline__ Edge nt_load_edge(const Edge* p) {
    EDI u; u.i = __builtin_nontemporal_load((const i2_ext*)p);
    return u.e;
}

__device__ __forceinline__ h8 to_h8(float4 lo, float4 hi) {
    h8 r;
    r.a = __floats2half2_rn(lo.x, lo.y); r.b = __floats2half2_rn(lo.z, lo.w);
    r.c = __floats2half2_rn(hi.x, hi.y); r.d = __floats2half2_rn(hi.z, hi.w);
    return r;
}
__device__ __forceinline__ void h8_to_f(h8 h, float4& lo, float4& hi) {
    float2 p = __half22float2(h.a), q = __half22float2(h.b);
    float2 s = __half22float2(h.c), t = __half22float2(h.d);
    lo = make_float4(p.x, p.y, q.x, q.y);
    hi = make_float4(s.x, s.y, t.x, t.y);
}
__device__ __forceinline__ void fma4(float4& a, float v, float4 x) {
    a.x += v * x.x; a.y += v * x.y; a.z += v * x.z; a.w += v * x.w;
}
__device__ __forceinline__ float4 add4(float4 a, float4 b) {
    return make_float4(a.x + b.x, a.y + b.y, a.z + b.z, a.w + b.w);
}

// ---------------------------------------------------------------------------
// Fused: conv (E16 = fp16(concat(uE,iE)), threads [0,CONV_T)) + histogram
// (threads [CONV_T, CONV_T+NE_ALL)). Independent work, one launch.
// ---------------------------------------------------------------------------
__global__ void conv_hist_kernel(const float4* __restrict__ uE,
                                 const float4* __restrict__ iE,
                                 h8* __restrict__ E16,
                                 const int* __restrict__ ar,
                                 const int* __restrict__ ur,
                                 int* __restrict__ cnt) {
    int t = blockIdx.x * blockDim.x + threadIdx.x;
    if (t < CONV_T) {
        int f4i = t * 2;                       // global float4 index (concat)
        const int ub = USER_N * NV4;
        float4 lo, hi;
        if (f4i < ub) { lo = nt_load4(uE + f4i);        hi = nt_load4(uE + f4i + 1); }
        else          { lo = nt_load4(iE + (f4i - ub)); hi = nt_load4(iE + (f4i - ub) + 1); }
        E16[t] = to_h8(lo, hi);
    } else {
        int i = t - CONV_T;
        if (i < N_EDGES_C)   atomicAdd(&cnt[ar[i]], 1);
        else if (i < NE_ALL) atomicAdd(&cnt[ur[i - N_EDGES_C] + N_TOTAL], 1);
    }
}

// ---------------------------------------------------------------------------
// scan (3 kernels) + scatter into packed Edge array
// ---------------------------------------------------------------------------
__global__ void scan_block_kernel(const int* __restrict__ cnt,
                                  int* __restrict__ rptr,
                                  int* __restrict__ bsum, int n) {
    __shared__ int s[SCAN_B];
    int i = blockIdx.x * SCAN_B + threadIdx.x;
    int v = (i < n) ? cnt[i] : 0;
    s[threadIdx.x] = v;
    __syncthreads();
    for (int off = 1; off < SCAN_B; off <<= 1) {
        int t = (threadIdx.x >= off) ? s[threadIdx.x - off] : 0;
        __syncthreads();
        s[threadIdx.x] += t;
        __syncthreads();
    }
    if (i < n) rptr[i] = s[threadIdx.x] - v;
    if (threadIdx.x == SCAN_B - 1) bsum[blockIdx.x] = s[threadIdx.x];
}

__global__ void scan_bsum_kernel(int* __restrict__ bsum, int nb) {
    __shared__ int s[SCAN_B];
    __shared__ int carry;
    if (threadIdx.x == 0) carry = 0;
    __syncthreads();
    for (int base = 0; base < nb; base += SCAN_B) {
        int i = base + threadIdx.x;
        int v = (i < nb) ? bsum[i] : 0;
        s[threadIdx.x] = v;
        __syncthreads();
        for (int off = 1; off < SCAN_B; off <<= 1) {
            int t = (threadIdx.x >= off) ? s[threadIdx.x - off] : 0;
            __syncthreads();
            s[threadIdx.x] += t;
            __syncthreads();
        }
        if (i < nb) bsum[i] = s[threadIdx.x] - v + carry;
        __syncthreads();
        if (threadIdx.x == 0) carry += s[SCAN_B - 1];
        __syncthreads();
    }
}

__global__ void scan_add_kernel(int* __restrict__ rptr, const int* __restrict__ bsum,
                                int* __restrict__ cursor, int n, int n_edges) {
    int i = blockIdx.x * blockDim.x + threadIdx.x;
    if (i < n) {
        int v = rptr[i] + bsum[i / SCAN_B];
        rptr[i]   = v;
        cursor[i] = v;
    }
    if (i == 0) rptr[n] = n_edges;
}

__global__ void scatter2_kernel(const int* __restrict__ ar, const int* __restrict__ ac,
                                const float* __restrict__ av,
                                const int* __restrict__ ur, const int* __restrict__ uc,
                                const float* __restrict__ uv,
                                int* __restrict__ cursor,
                                Edge* __restrict__ edges) {
    int i = blockIdx.x * blockDim.x + threadIdx.x;
    int r; Edge ed;
    if (i < N_EDGES_C)      { r = ar[i];             ed.c = ac[i];           ed.v = av[i]; }
    else if (i < NE_ALL)    { int j = i - N_EDGES_C; r = ur[j] + N_TOTAL; ed.c = uc[j] + N_TOTAL; ed.v = uv[j]; }
    else return;
    int pos = atomicAdd(&cursor[r], 1);
    edges[pos] = ed;
}

// col c -> row in E16 (user-graph cols shifted by N_TOTAL)
__device__ __forceinline__ int e16_row(int c) {
    return (c < N_TOTAL) ? c : c - N_TOTAL;
}

// ---------------------------------------------------------------------------
// pass1: l1 = A*e0 gathering h8 rows from E16. 16 lanes/row.
// ---------------------------------------------------------------------------
__global__ void spmm_pass1(const int* __restrict__ rptr,
                           const Edge* __restrict__ edges,
                           const h8* __restrict__ E16,
                           h8* __restrict__ cur1) {
    int t = blockIdx.x * blockDim.x + threadIdx.x;
    int r = t >> 4, sub = t & 15;
    if (r >= NR_ALL) return;
    int e0 = rptr[r], e1 = rptr[r + 1];

    float4 a0l = make_float4(0,0,0,0), a0h = a0l, a1l = a0l, a1h = a0l;
    int e = e0;
    for (; e + 2 <= e1; e += 2) {
        Edge d0 = edges[e], d1 = edges[e + 1];
        h8 h0 = E16[(size_t)e16_row(d0.c) * NV8 + sub];
        h8 h1 = E16[(size_t)e16_row(d1.c) * NV8 + sub];
        float4 lo, hi;
        h8_to_f(h0, lo, hi); fma4(a0l, d0.v, lo); fma4(a0h, d0.v, hi);
        h8_to_f(h1, lo, hi); fma4(a1l, d1.v, lo); fma4(a1h, d1.v, hi);
    }
    if (e < e1) {
        Edge d0 = edges[e];
        h8 h0 = E16[(size_t)e16_row(d0.c) * NV8 + sub];
        float4 lo, hi;
        h8_to_f(h0, lo, hi); fma4(a0l, d0.v, lo); fma4(a0h, d0.v, hi);
    }
    cur1[(size_t)r * NV8 + sub] = to_h8(add4(a0l, a1l), add4(a0h, a1h));
}

// ---------------------------------------------------------------------------
// pass2: l2 = A*l1. Main rows -> cur2 (h8). User rows -> uacc = e0+l1+l2 (f32 nt).
// ---------------------------------------------------------------------------
__global__ void spmm_pass2(const int* __restrict__ rptr,
                           const Edge* __restrict__ edges,
                           const h8* __restrict__ cur1,
                           const h8* __restrict__ E16,
                           h8* __restrict__ cur2,
                           float4* __restrict__ uacc) {
    int t = blockIdx.x * blockDim.x + threadIdx.x;
    int r = t >> 4, sub = t & 15;
    if (r >= NR_ALL) return;
    int e0 = rptr[r], e1 = rptr[r + 1];

    float4 a0l = make_float4(0,0,0,0), a0h = a0l, a1l = a0l, a1h = a0l;
    int e = e0;
    for (; e + 2 <= e1; e += 2) {
        Edge d0 = edges[e], d1 = edges[e + 1];
        h8 h0 = cur1[(size_t)d0.c * NV8 + sub];
        h8 h1 = cur1[(size_t)d1.c * NV8 + sub];
        float4 lo, hi;
        h8_to_f(h0, lo, hi); fma4(a0l, d0.v, lo); fma4(a0h, d0.v, hi);
        h8_to_f(h1, lo, hi); fma4(a1l, d1.v, lo); fma4(a1h, d1.v, hi);
    }
    if (e < e1) {
        Edge d0 = edges[e];
        h8 h0 = cur1[(size_t)d0.c * NV8 + sub];
        float4 lo, hi;
        h8_to_f(h0, lo, hi); fma4(a0l, d0.v, lo); fma4(a0h, d0.v, hi);
    }
    float4 al = add4(a0l, a1l), ah = add4(a0h, a1h);

    size_t o = (size_t)r * NV8 + sub;
    if (r < N_TOTAL) {
        cur2[o] = to_h8(al, ah);
    } else {
        int ur = r - N_TOTAL;
        float4 u0l, u0h, l1l, l1h;
        h8_to_f(E16[(size_t)ur * NV8 + sub], u0l, u0h);
        h8_to_f(cur1[o], l1l, l1h);
        size_t of4 = (size_t)ur * NV4 + sub * 2;
        nt_store4(uacc + of4,     add4(add4(u0l, l1l), al));
        nt_store4(uacc + of4 + 1, add4(add4(u0h, l1h), ah));
    }
}

// ---------------------------------------------------------------------------
// pass3 (main rows): l3 = A*l2; acc = e0+l1+l2+l3 (f32 nt). Last use of
// E16/cur1 -> nt loads keep cur2 gather table L3-resident.
// ---------------------------------------------------------------------------
__global__ void spmm_pass3(const int* __restrict__ rptr,
                           const Edge* __restrict__ edges,
                           const h8* __restrict__ cur2,
                           const h8* __restrict__ cur1,
                           const h8* __restrict__ E16,
                           float4* __restrict__ acc) {
    int t = blockIdx.x * blockDim.x + threadIdx.x;
    int r = t >> 4, sub = t & 15;
    if (r >= N_TOTAL) return;
    int e0 = rptr[r], e1 = rptr[r + 1];

    float4 a0l = make_float4(0,0,0,0), a0h = a0l, a1l = a0l, a1h = a0l;
    int e = e0;
    for (; e + 2 <= e1; e += 2) {
        Edge d0 = nt_load_edge(edges + e), d1 = nt_load_edge(edges + e + 1);
        h8 h0 = cur2[(size_t)d0.c * NV8 + sub];
        h8 h1 = cur2[(size_t)d1.c * NV8 + sub];
        float4 lo, hi;
        h8_to_f(h0, lo, hi); fma4(a0l, d0.v, lo); fma4(a0h, d0.v, hi);
        h8_to_f(h1, lo, hi); fma4(a1l, d1.v, lo); fma4(a1h, d1.v, hi);
    }
    if (e < e1) {
        Edge d0 = nt_load_edge(edges + e);
        h8 h0 = cur2[(size_t)d0.c * NV8 + sub];
        float4 lo, hi;
        h8_to_f(h0, lo, hi); fma4(a0l, d0.v, lo); fma4(a0h, d0.v, hi);
    }
    float4 al = add4(a0l, a1l), ah = add4(a0h, a1h);

    size_t o = (size_t)r * NV8 + sub;
    float4 ezl, ezh, l1l, l1h, l2l, l2h;
    h8_to_f(nt_load_h8(E16 + o),  ezl, ezh);
    h8_to_f(nt_load_h8(cur1 + o), l1l, l1h);
    h8_to_f(cur2[o], l2l, l2h);

    size_t of4 = (size_t)r * NV4 + sub * 2;
    nt_store4(acc + of4,     add4(add4(ezl, l1l), add4(l2l, al)));
    nt_store4(acc + of4 + 1, add4(add4(ezh, l1h), add4(l2h, ah)));
}

// ---------------------------------------------------------------------------
extern "C" void kernel_launch(void* const* d_in, const int* in_sizes, int n_in,
                              void* d_out, int out_size, void* d_ws, size_t ws_size,
                              hipStream_t stream) {
    const float* uE    = (const float*)d_in[0];
    const float* iE    = (const float*)d_in[1];
    const int*   arows = (const int*)  d_in[2];
    const int*   acols = (const int*)  d_in[3];
    const float* avals = (const float*)d_in[4];
    const int*   urows = (const int*)  d_in[5];
    const int*   ucols = (const int*)  d_in[6];
    const float* uvals = (const float*)d_in[7];

    float* acc  = (float*)d_out;                              // N_TOTAL x 128 f32
    float* uacc = acc + (size_t)N_TOTAL * LATDIM;             // USER_N x 128 f32

    // workspace layout
    h8*    E16  = (h8*)d_ws;                                  // N_TOTAL*NV8  (76.8 MB)
    h8*    cur1 = E16 + (size_t)N_TOTAL * NV8;                // NR_ALL*NV8   (102.4 MB)
    h8*    cur2 = cur1 + (size_t)NR_ALL * NV8;                // N_TOTAL*NV8  (76.8 MB)
    int*   cnt  = (int*)(cur2 + (size_t)N_TOTAL * NV8);       // NR_ALL
    int*   rptr = cnt + NR_ALL;                               // NR_ALL+1
    int*   curp = rptr + NR_ALL + 1;                          // NR_ALL
    int*   bsum = curp + NR_ALL;                              // 4096
    Edge*  edges = (Edge*)(bsum + 4096);                      // NE_ALL (7.2 MB)

    const int TB = 256;

    // ---- fused conv + histogram ----
    hipMemsetAsync(cnt, 0, NR_ALL * sizeof(int), stream);
    {
        int threads = CONV_T + NE_ALL;
        conv_hist_kernel<<<(threads + TB - 1) / TB, TB, 0, stream>>>(
            (const float4*)uE, (const float4*)iE, E16, arows, urows, cnt);
    }
    // ---- scan + scatter ----
    {
        int nb = (NR_ALL + SCAN_B - 1) / SCAN_B;
        scan_block_kernel<<<nb, SCAN_B, 0, stream>>>(cnt, rptr, bsum, NR_ALL);
        scan_bsum_kernel<<<1, SCAN_B, 0, stream>>>(bsum, nb);
        scan_add_kernel<<<(NR_ALL + TB - 1) / TB, TB, 0, stream>>>(
            rptr, bsum, curp, NR_ALL, NE_ALL);
    }
    scatter2_kernel<<<(NE_ALL + TB - 1) / TB, TB, 0, stream>>>(
        arows, acols, avals, urows, ucols, uvals, curp, edges);

    // ---- three fused SpMM passes (16 lanes/row) ----
    {
        int threads = NR_ALL * NV8;
        int grid = (threads + TB - 1) / TB;
        spmm_pass1<<<grid, TB, 0, stream>>>(rptr, edges, E16, cur1);
        spmm_pass2<<<grid, TB, 0, stream>>>(rptr, edges, cur1, E16,
                                            cur2, (float4*)uacc);
    }
    {
        int threads = N_TOTAL * NV8;
        int grid = (threads + TB - 1) / TB;
        spmm_pass3<<<grid, TB, 0, stream>>>(rptr, edges, cur2, cur1, E16,
                                            (float4*)acc);
    }
}